// Round 3
// baseline (282.779 us; speedup 1.0000x reference)
//
#include <hip/hip_runtime.h>

#define NN 20000
#define EE 20000

typedef __attribute__((ext_vector_type(8))) short short8;
typedef __attribute__((ext_vector_type(4))) float f32x4;

// workspace layout (floats)
#define WS_AGG 0
#define WS_NUM (NN*64)
#define WS_CNT (NN*67)
#define WS_TOTAL (NN*68)
#define WS1S_ELEMS (4096*128)   // bf16 elems of swizzled 64*Ws1 (1 MB)

// LDS float offsets
#define OFF_SIN  0       // s_in [64][129]=8256 ; later t1 [128][65]=8320
#define OFF_E1   8320    // e1 [64 f][64 e] ; later ef [64 o][64 e]   (4096)
#define OFF_G2   12416   // g f32 [64 i][64 e] ; later v [64 f][64 e] (4096)
#define OFF_GBF  16512   // g bf16 swizzled [64 e][128 B]             (2048)
#define SM_FLOATS 18560  // 74.2 KB

__device__ __forceinline__ float siluf(float x) {
    return x * (1.0f / (1.0f + __expf(-x)));
}
__device__ __forceinline__ unsigned short f2bf(float f) {
    union { float f; unsigned u; } v; v.f = f;
    return (unsigned short)((v.u + 0x7FFF + ((v.u >> 16) & 1)) >> 16);
}

// out[((s*8+tn)*64 + l)*8 + u] = bf16(64*Ws1[(s*32 + 8*(l>>4) + u)][tn*16 + (l&15)])
__global__ void swz_ws1(const float* __restrict__ Ws1, unsigned short* __restrict__ out) {
    const int tid = blockIdx.x * 256 + threadIdx.x;   // 65536 threads
    const int l = tid & 63, fid = tid >> 6;
    const int s = fid >> 3, tn = fid & 7;
    const int krow = s * 32 + 8 * (l >> 4);
    const int ncol = tn * 16 + (l & 15);
    short8 frag;
    #pragma unroll
    for (int u = 0; u < 8; ++u)
        frag[u] = (short)f2bf(64.0f * Ws1[(krow + u) * 128 + ncol]);
    *(short8*)&out[(size_t)tid * 8] = frag;
}

__global__ __launch_bounds__(512, 4)
void egcl_edge_kernel(const float* __restrict__ h, const float* __restrict__ coord,
                      const int* __restrict__ ei,
                      const float* __restrict__ We1, const float* __restrict__ be1,
                      const float* __restrict__ We2, const float* __restrict__ be2,
                      const unsigned short* __restrict__ Ws1s, const float* __restrict__ bs1,
                      const float* __restrict__ Ws2, const float* __restrict__ bs2,
                      const float* __restrict__ Wc1, const float* __restrict__ bc1,
                      const float* __restrict__ Wc2,
                      float* __restrict__ ws)
{
    __shared__ __attribute__((aligned(16))) float sm[SM_FLOATS];
    __shared__ int s_row[64], s_col[64];
    __shared__ float s_cd[192], s_rad[64];

    const int t = threadIdx.x;
    const int e0 = blockIdx.x * 64;

    if (t < 64) {
        const int eid = min(e0 + t, EE - 1);
        const int r = ei[eid], c = ei[EE + eid];
        s_row[t] = r; s_col[t] = c;
        const float dx = coord[r*3+0] - coord[c*3+0];
        const float dy = coord[r*3+1] - coord[c*3+1];
        const float dz = coord[r*3+2] - coord[c*3+2];
        s_cd[t] = dx; s_cd[64+t] = dy; s_cd[128+t] = dz;
        s_rad[t] = dx*dx + dy*dy + dz*dz;
    }
    __syncthreads();

    // gather: s_in[e][129] = [h[row], h[col], radial]
    {
        const int e = t >> 3, seg = t & 7;
        const int r = s_row[e], c = s_col[e];
        float* din = &sm[OFF_SIN + e*129];
        #pragma unroll
        for (int u = 0; u < 8; ++u) din[seg*8 + u] = h[r*64 + seg*8 + u];
        #pragma unroll
        for (int u = 0; u < 8; ++u) din[64 + seg*8 + u] = h[c*64 + seg*8 + u];
        if (seg == 0) din[128] = s_rad[e];
    }
    __syncthreads();

    const int e = t & 63, og = t >> 6;   // og uniform per wave -> weight reads scalarize

    // e1 = silu(in @ We1 + be1) -> OFF_E1 [feat][edge]
    {
        float acc[8];
        #pragma unroll
        for (int u = 0; u < 8; ++u) acc[u] = be1[og*8 + u];
        const float* din = &sm[OFF_SIN + e*129];
        for (int q = 0; q < 129; ++q) {
            const float x = din[q];
            const float* wr = &We1[q*64 + og*8];
            #pragma unroll
            for (int u = 0; u < 8; ++u) acc[u] = fmaf(x, wr[u], acc[u]);
        }
        #pragma unroll
        for (int u = 0; u < 8; ++u) sm[OFF_E1 + (og*8+u)*64 + e] = siluf(acc[u]);
    }
    __syncthreads();

    // g = silu(e1 @ We2 + be2) -> f32 [i][e] at OFF_G2, bf16 swizzled [e][k] at OFF_GBF
    {
        float acc[8];
        #pragma unroll
        for (int u = 0; u < 8; ++u) acc[u] = be2[og*8 + u];
        for (int q = 0; q < 64; ++q) {
            const float x = sm[OFF_E1 + q*64 + e];
            const float* wr = &We2[q*64 + og*8];
            #pragma unroll
            for (int u = 0; u < 8; ++u) acc[u] = fmaf(x, wr[u], acc[u]);
        }
        short8 frag;
        #pragma unroll
        for (int u = 0; u < 8; ++u) {
            const float s = siluf(acc[u]);
            sm[OFF_G2 + (og*8+u)*64 + e] = s;
            frag[u] = (short)f2bf(s);
        }
        *(short8*)((char*)sm + OFF_GBF*4 + e*128 + ((og ^ (e & 7)) * 16)) = frag;
    }
    __syncthreads();

    // ---- SO3 GEMM: acc[e,k] = sum_i g[e,i] * (g_bf16[e,:] @ 64*Ws1_i[:,k])
    // wave w owns cols [w*16,+16); per K-32 sub-iter exactly ONE 16B/lane B load.
    const int l = t & 63, w = t >> 6;
    const int kg = l >> 4;

    short8 A[4][2];
    #pragma unroll
    for (int et = 0; et < 4; ++et) {
        const int er = et*16 + (l & 15);
        #pragma unroll
        for (int kh = 0; kh < 2; ++kh)
            A[et][kh] = *(const short8*)((const char*)sm + OFF_GBF*4 + er*128 +
                                         (((kh*4 + kg) ^ (er & 7)) * 16));
    }

    float accv[4][4];
    #pragma unroll
    for (int et = 0; et < 4; ++et)
        #pragma unroll
        for (int r = 0; r < 4; ++r) accv[et][r] = 0.0f;

    const short8* Bp = (const short8*)Ws1s;
    // B frag for sub-iter s: Bp[((s*8 + w)*64 + l)]
    short8 b[8];
    #pragma unroll
    for (int u = 0; u < 8; ++u) b[u] = Bp[((u*8 + w)*64 + l)];

    f32x4 ci[4];

#define SUBITER(S8, U) { \
    const int s_ = (S8)*8 + (U); \
    if (((U) & 1) == 0) { \
        _Pragma("unroll") \
        for (int et = 0; et < 4; ++et) \
            ci[et] = __builtin_amdgcn_mfma_f32_16x16x32_bf16(A[et][0], b[U], (f32x4){0.f,0.f,0.f,0.f}, 0, 0, 0); \
    } else { \
        _Pragma("unroll") \
        for (int et = 0; et < 4; ++et) \
            ci[et] = __builtin_amdgcn_mfma_f32_16x16x32_bf16(A[et][1], b[U], ci[et], 0, 0, 0); \
        const int i_ = s_ >> 1; \
        _Pragma("unroll") \
        for (int et = 0; et < 4; ++et) { \
            const f32x4 g4 = *(const f32x4*)&sm[OFF_G2 + i_*64 + et*16 + (kg << 2)]; \
            _Pragma("unroll") \
            for (int r = 0; r < 4; ++r) accv[et][r] = fmaf(g4[r], ci[et][r], accv[et][r]); \
        } \
    } \
}

    for (int s8 = 0; s8 < 15; ++s8) {
        #pragma unroll
        for (int u = 0; u < 8; ++u) {
            SUBITER(s8, u);
            b[u] = Bp[((((s8+1)*8 + u)*8 + w)*64 + l)];   // prefetch s+8
        }
    }
    #pragma unroll
    for (int u = 0; u < 8; ++u) { SUBITER(15, u); }
#undef SUBITER

    // t1 = relu(acc + bs1) -> OFF_SIN region, [col][65]
    {
        const int col = w*16 + (l & 15);
        const float bk = bs1[col];
        #pragma unroll
        for (int et = 0; et < 4; ++et)
            #pragma unroll
            for (int r = 0; r < 4; ++r)
                sm[OFF_SIN + col*65 + et*16 + (kg << 2) + r] = fmaxf(accv[et][r] + bk, 0.0f);
    }
    __syncthreads();

    // edge_feat = t1 @ Ws2 + bs2 -> ef [o][e] at OFF_E1
    {
        float a2[8];
        #pragma unroll
        for (int u = 0; u < 8; ++u) a2[u] = bs2[og*8 + u];
        for (int k = 0; k < 128; ++k) {
            const float x = sm[OFF_SIN + k*65 + e];
            const float* wr = &Ws2[k*64 + og*8];
            #pragma unroll
            for (int u = 0; u < 8; ++u) a2[u] = fmaf(x, wr[u], a2[u]);
        }
        #pragma unroll
        for (int u = 0; u < 8; ++u) sm[OFF_E1 + (og*8+u)*64 + e] = a2[u];
    }
    __syncthreads();

    // v = silu(ef @ Wc1 + bc1) -> OFF_G2 [f][e]
    {
        float a3[8];
        #pragma unroll
        for (int u = 0; u < 8; ++u) a3[u] = bc1[og*8 + u];
        for (int q = 0; q < 64; ++q) {
            const float x = sm[OFF_E1 + q*64 + e];
            const float* wr = &Wc1[q*64 + og*8];
            #pragma unroll
            for (int u = 0; u < 8; ++u) a3[u] = fmaf(x, wr[u], a3[u]);
        }
        #pragma unroll
        for (int u = 0; u < 8; ++u) sm[OFF_G2 + (og*8+u)*64 + e] = siluf(a3[u]);
    }
    __syncthreads();

    // coord weight + scatter num/cnt
    if (t < 64 && e0 + t < EE) {
        float cw = 0.0f;
        for (int f = 0; f < 64; ++f) cw = fmaf(sm[OFF_G2 + f*64 + t], Wc2[f], cw);
        const int r = s_row[t];
        atomicAdd(&ws[WS_NUM + r*3 + 0], s_cd[t]     * cw);
        atomicAdd(&ws[WS_NUM + r*3 + 1], s_cd[64+t]  * cw);
        atomicAdd(&ws[WS_NUM + r*3 + 2], s_cd[128+t] * cw);
        atomicAdd(&ws[WS_CNT + r], 1.0f);
    }
    // scatter agg (edge_feat per row)
    if (e0 + e < EE) {
        const int r = s_row[e];
        #pragma unroll
        for (int u = 0; u < 8; ++u) {
            const int o = og*8 + u;
            atomicAdd(&ws[WS_AGG + r*64 + o], sm[OFF_E1 + o*64 + e]);
        }
    }
}

__global__ __launch_bounds__(256, 2)
void egcl_node_kernel(const float* __restrict__ h, const float* __restrict__ coord,
                      const int* __restrict__ ei,
                      const float* __restrict__ Wn1, const float* __restrict__ bn1,
                      const float* __restrict__ Wn2, const float* __restrict__ bn2,
                      const float* __restrict__ ws, float* __restrict__ out)
{
    __shared__ float s_m[131*32];
    __shared__ float s_z[64*32];
    const int t = threadIdx.x;
    const int n0 = blockIdx.x * 32;

    {
        const int n = t >> 3, seg = t & 7;
        const float* hp = &h[(n0+n)*64 + seg*8];
        #pragma unroll
        for (int u = 0; u < 8; ++u) s_m[(seg*8+u)*32 + n] = hp[u];
        const float* ap = &ws[WS_AGG + (n0+n)*64 + seg*8];
        #pragma unroll
        for (int u = 0; u < 8; ++u) s_m[(67+seg*8+u)*32 + n] = ap[u];
    }
    if (t < 32) {
        const int n = n0 + t;
        const int r = ei[n], c = ei[EE + n];
        const float dx = coord[r*3+0] - coord[c*3+0];
        const float dy = coord[r*3+1] - coord[c*3+1];
        const float dz = coord[r*3+2] - coord[c*3+2];
        const float inv = 1.0f / (sqrtf(dx*dx + dy*dy + dz*dz) + 1e-8f);
        s_m[64*32 + t] = dx*inv;
        s_m[65*32 + t] = dy*inv;
        s_m[66*32 + t] = dz*inv;
        const float cnt = fmaxf(ws[WS_CNT + n], 1.0f);
        out[NN*67 + n*3 + 0] = coord[n*3+0] + ws[WS_NUM + n*3 + 0] / cnt;
        out[NN*67 + n*3 + 1] = coord[n*3+1] + ws[WS_NUM + n*3 + 1] / cnt;
        out[NN*67 + n*3 + 2] = coord[n*3+2] + ws[WS_NUM + n*3 + 2] / cnt;
    }
    __syncthreads();

    {
        const int n = t & 31, og = t >> 5;
        float acc[8];
        #pragma unroll
        for (int u = 0; u < 8; ++u) acc[u] = bn1[og*8 + u];
        for (int q = 0; q < 131; ++q) {
            const float x = s_m[q*32 + n];
            const float* wr = &Wn1[q*64 + og*8];
            #pragma unroll
            for (int u = 0; u < 8; ++u) acc[u] = fmaf(x, wr[u], acc[u]);
        }
        #pragma unroll
        for (int u = 0; u < 8; ++u) s_z[(og*8+u)*32 + n] = siluf(acc[u]);
    }
    __syncthreads();

    {
        const int n = t & 31, og = t >> 5;
        for (int o = og; o < 67; o += 8) {
            float a = s_m[o*32 + n] + bn2[o];
            for (int k = 0; k < 64; ++k)
                a = fmaf(s_z[k*32 + n], Wn2[k*67 + o], a);
            out[(n0 + n)*67 + o] = a;
        }
    }
}

extern "C" void kernel_launch(void* const* d_in, const int* in_sizes, int n_in,
                              void* d_out, int out_size, void* d_ws, size_t ws_size,
                              hipStream_t stream)
{
    (void)in_sizes; (void)n_in; (void)out_size;
    const float* h     = (const float*)d_in[0];
    const float* coord = (const float*)d_in[1];
    const int*   ei    = (const int*)d_in[2];
    const float* We1   = (const float*)d_in[3];
    const float* be1   = (const float*)d_in[4];
    const float* We2   = (const float*)d_in[5];
    const float* be2   = (const float*)d_in[6];
    const float* Ws1   = (const float*)d_in[7];
    const float* bs1   = (const float*)d_in[8];
    const float* Ws2   = (const float*)d_in[9];
    const float* bs2   = (const float*)d_in[10];
    const float* Wc1   = (const float*)d_in[11];
    const float* bc1   = (const float*)d_in[12];
    const float* Wc2   = (const float*)d_in[13];
    const float* Wn1   = (const float*)d_in[14];
    const float* bn1   = (const float*)d_in[15];
    const float* Wn2   = (const float*)d_in[16];
    const float* bn2   = (const float*)d_in[17];
    float* ws  = (float*)d_ws;
    float* out = (float*)d_out;

    const size_t need = (size_t)WS_TOTAL * sizeof(float) + (size_t)WS1S_ELEMS * 2;
    unsigned short* ws1s = (ws_size >= need) ? (unsigned short*)(ws + WS_TOTAL)
                                             : (unsigned short*)d_out;  // node kernel rewrites d_out afterwards

    hipMemsetAsync(d_ws, 0, (size_t)WS_TOTAL * sizeof(float), stream);
    swz_ws1<<<256, 256, 0, stream>>>(Ws1, ws1s);
    egcl_edge_kernel<<<(EE + 63)/64, 512, 0, stream>>>(h, coord, ei, We1, be1, We2, be2,
                                                       ws1s, bs1, Ws2, bs2, Wc1, bc1, Wc2, ws);
    egcl_node_kernel<<<NN/32, 256, 0, stream>>>(h, coord, ei, Wn1, bn1, Wn2, bn2, ws, out);
}

// Round 4
// 280.203 us; speedup vs baseline: 1.0092x; 1.0092x over previous
//
#include <hip/hip_runtime.h>

#define NN 20000
#define EE 20000

typedef __attribute__((ext_vector_type(8))) short short8;
typedef __attribute__((ext_vector_type(4))) float f32x4;

// workspace layout (floats)
#define WS_AGG 0
#define WS_NUM (NN*64)
#define WS_CNT (NN*67)
#define WS_TOTAL (NN*68)
#define WS1S_ELEMS (4096*128)   // bf16 elems of swizzled 64*Ws1 (1 MB)

// LDS float offsets
#define OFF_SIN  0       // s_in [64][129]=8256 ; B ping-pong 2x8KB during GEMM ; t1 [128][65]=8320 after
#define OFF_E1   8320    // e1 [64 f][64 e] ; later ef [64 o][64 e]   (4096)
#define OFF_G2   12416   // g f32 [64 i][64 e] ; later v [64 f][64 e] (4096)
#define OFF_GBF  16512   // g bf16 swizzled [64 e][128 B]             (2048)
#define SM_FLOATS 18560  // 74.2 KB

__device__ __forceinline__ float siluf(float x) {
    return x * (1.0f / (1.0f + __expf(-x)));
}
__device__ __forceinline__ unsigned short f2bf(float f) {
    union { float f; unsigned u; } v; v.f = f;
    return (unsigned short)((v.u + 0x7FFF + ((v.u >> 16) & 1)) >> 16);
}
// async 16B/lane global->LDS; lds base must be wave-uniform (HW adds lane*16)
__device__ __forceinline__ void stage16(const void* gsrc, void* lds_wave_base) {
    __builtin_amdgcn_global_load_lds(
        (const __attribute__((address_space(1))) unsigned int*)gsrc,
        (__attribute__((address_space(3))) unsigned int*)lds_wave_base, 16, 0, 0);
}

// out[((s*8+tn)*64 + l)*8 + u] = bf16(64*Ws1[(s*32 + 8*(l>>4) + u)][tn*16 + (l&15)])
__global__ void swz_ws1(const float* __restrict__ Ws1, unsigned short* __restrict__ out) {
    const int tid = blockIdx.x * 256 + threadIdx.x;   // 65536 threads
    const int l = tid & 63, fid = tid >> 6;
    const int s = fid >> 3, tn = fid & 7;
    const int krow = s * 32 + 8 * (l >> 4);
    const int ncol = tn * 16 + (l & 15);
    short8 frag;
    #pragma unroll
    for (int u = 0; u < 8; ++u)
        frag[u] = (short)f2bf(64.0f * Ws1[(krow + u) * 128 + ncol]);
    *(short8*)&out[(size_t)tid * 8] = frag;
}

__global__ __launch_bounds__(512) __attribute__((amdgpu_waves_per_eu(4, 4)))
void egcl_edge_kernel(const float* __restrict__ h, const float* __restrict__ coord,
                      const int* __restrict__ ei,
                      const float* __restrict__ We1, const float* __restrict__ be1,
                      const float* __restrict__ We2, const float* __restrict__ be2,
                      const unsigned short* __restrict__ Ws1s, const float* __restrict__ bs1,
                      const float* __restrict__ Ws2, const float* __restrict__ bs2,
                      const float* __restrict__ Wc1, const float* __restrict__ bc1,
                      const float* __restrict__ Wc2,
                      float* __restrict__ ws)
{
    __shared__ __attribute__((aligned(16))) float sm[SM_FLOATS];
    __shared__ int s_row[64], s_col[64];
    __shared__ float s_cd[192], s_rad[64];

    const int t = threadIdx.x;
    const int e0 = blockIdx.x * 64;

    if (t < 64) {
        const int eid = min(e0 + t, EE - 1);
        const int r = ei[eid], c = ei[EE + eid];
        s_row[t] = r; s_col[t] = c;
        const float dx = coord[r*3+0] - coord[c*3+0];
        const float dy = coord[r*3+1] - coord[c*3+1];
        const float dz = coord[r*3+2] - coord[c*3+2];
        s_cd[t] = dx; s_cd[64+t] = dy; s_cd[128+t] = dz;
        s_rad[t] = dx*dx + dy*dy + dz*dz;
    }
    __syncthreads();

    // gather: s_in[e][129] = [h[row], h[col], radial]
    {
        const int e = t >> 3, seg = t & 7;
        const int r = s_row[e], c = s_col[e];
        float* din = &sm[OFF_SIN + e*129];
        #pragma unroll
        for (int u = 0; u < 8; ++u) din[seg*8 + u] = h[r*64 + seg*8 + u];
        #pragma unroll
        for (int u = 0; u < 8; ++u) din[64 + seg*8 + u] = h[c*64 + seg*8 + u];
        if (seg == 0) din[128] = s_rad[e];
    }
    __syncthreads();

    const int e = t & 63, og = t >> 6;   // og uniform per wave -> weight reads scalarize

    // e1 = silu(in @ We1 + be1) -> OFF_E1 [feat][edge]
    {
        float acc[8];
        #pragma unroll
        for (int u = 0; u < 8; ++u) acc[u] = be1[og*8 + u];
        const float* din = &sm[OFF_SIN + e*129];
        for (int q = 0; q < 129; ++q) {
            const float x = din[q];
            const float* wr = &We1[q*64 + og*8];
            #pragma unroll
            for (int u = 0; u < 8; ++u) acc[u] = fmaf(x, wr[u], acc[u]);
        }
        #pragma unroll
        for (int u = 0; u < 8; ++u) sm[OFF_E1 + (og*8+u)*64 + e] = siluf(acc[u]);
    }
    __syncthreads();

    // g = silu(e1 @ We2 + be2) -> f32 [i][e] at OFF_G2, bf16 swizzled [e][k] at OFF_GBF
    {
        float acc[8];
        #pragma unroll
        for (int u = 0; u < 8; ++u) acc[u] = be2[og*8 + u];
        for (int q = 0; q < 64; ++q) {
            const float x = sm[OFF_E1 + q*64 + e];
            const float* wr = &We2[q*64 + og*8];
            #pragma unroll
            for (int u = 0; u < 8; ++u) acc[u] = fmaf(x, wr[u], acc[u]);
        }
        short8 frag;
        #pragma unroll
        for (int u = 0; u < 8; ++u) {
            const float s = siluf(acc[u]);
            sm[OFF_G2 + (og*8+u)*64 + e] = s;
            frag[u] = (short)f2bf(s);
        }
        *(short8*)((char*)sm + OFF_GBF*4 + e*128 + ((og ^ (e & 7)) * 16)) = frag;
    }
    __syncthreads();

    // ---- SO3 GEMM: acc[e,k] = sum_i g[e,i] * (g_bf16[e,:] @ 64*Ws1_i[:,k])
    // wave w owns cols [w*16,+16). B-stream: 128 steps x 8KB via global_load_lds
    // into a 2x8KB ping-pong at OFF_SIN. Each wave stages/reads ONLY its own 1KB
    // (dst lane-linear = t*16) => fully wave-private pipeline, NO barriers,
    // counted s_waitcnt vmcnt(1).
    const int l = t & 63, w = t >> 6;
    const int kg = l >> 4;

    short8 A[4][2];
    #pragma unroll
    for (int et = 0; et < 4; ++et) {
        const int er = et*16 + (l & 15);
        #pragma unroll
        for (int kh = 0; kh < 2; ++kh)
            A[et][kh] = *(const short8*)((const char*)sm + OFF_GBF*4 + er*128 +
                                         (((kh*4 + kg) ^ (er & 7)) * 16));
    }

    float accv[4][4];
    #pragma unroll
    for (int et = 0; et < 4; ++et)
        #pragma unroll
        for (int r = 0; r < 4; ++r) accv[et][r] = 0.0f;

    const char* Bsrc = (const char*)Ws1s;
    char* const P0 = (char*)sm;           // bytes [0, 8192)
    char* const P1 = (char*)sm + 8192;    // bytes [8192, 16384)
    char* const wb0 = P0 + w*1024;        // wave-uniform LDS dst bases
    char* const wb1 = P1 + w*1024;
    const int lane16 = t * 16;            // == (w*64 + l)*16 : own staged bytes

    // prologue: stage step 0 -> P0
    stage16(Bsrc + lane16, wb0);

    f32x4 ci[4];
#define MERGE(I) { \
    _Pragma("unroll") \
    for (int et = 0; et < 4; ++et) { \
        const f32x4 g4 = *(const f32x4*)&sm[OFF_G2 + (I)*64 + et*16 + (kg << 2)]; \
        _Pragma("unroll") \
        for (int r = 0; r < 4; ++r) accv[et][r] = fmaf(g4[r], ci[et][r], accv[et][r]); \
    } \
}

    #pragma unroll 1
    for (int i = 0; i < 63; ++i) {
        // step s0 = 2i from P0 ; stage s0+1 -> P1
        stage16(Bsrc + (2*i+1)*8192 + lane16, wb1);
        asm volatile("s_waitcnt vmcnt(1)" ::: "memory");
        __builtin_amdgcn_sched_barrier(0);
        {
            const short8 b0 = *(const short8*)(P0 + lane16);
            #pragma unroll
            for (int et = 0; et < 4; ++et)
                ci[et] = __builtin_amdgcn_mfma_f32_16x16x32_bf16(A[et][0], b0, (f32x4){0.f,0.f,0.f,0.f}, 0, 0, 0);
        }
        // step s1 = 2i+1 from P1 ; stage s1+1 -> P0
        stage16(Bsrc + (2*i+2)*8192 + lane16, wb0);
        asm volatile("s_waitcnt vmcnt(1)" ::: "memory");
        __builtin_amdgcn_sched_barrier(0);
        {
            const short8 b1 = *(const short8*)(P1 + lane16);
            #pragma unroll
            for (int et = 0; et < 4; ++et)
                ci[et] = __builtin_amdgcn_mfma_f32_16x16x32_bf16(A[et][1], b1, ci[et], 0, 0, 0);
        }
        MERGE(i);
    }
    {   // tail i = 63: steps 126 (in P0), 127 (in P1)
        stage16(Bsrc + 127*8192 + lane16, wb1);
        asm volatile("s_waitcnt vmcnt(1)" ::: "memory");
        __builtin_amdgcn_sched_barrier(0);
        {
            const short8 b0 = *(const short8*)(P0 + lane16);
            #pragma unroll
            for (int et = 0; et < 4; ++et)
                ci[et] = __builtin_amdgcn_mfma_f32_16x16x32_bf16(A[et][0], b0, (f32x4){0.f,0.f,0.f,0.f}, 0, 0, 0);
        }
        asm volatile("s_waitcnt vmcnt(0)" ::: "memory");
        __builtin_amdgcn_sched_barrier(0);
        {
            const short8 b1 = *(const short8*)(P1 + lane16);
            #pragma unroll
            for (int et = 0; et < 4; ++et)
                ci[et] = __builtin_amdgcn_mfma_f32_16x16x32_bf16(A[et][1], b1, ci[et], 0, 0, 0);
        }
        MERGE(63);
    }
#undef MERGE
    __syncthreads();   // all waves done reading B bufs; OFF_SIN region reused for t1

    // t1 = relu(acc + bs1) -> OFF_SIN region, [col][65]
    {
        const int col = w*16 + (l & 15);
        const float bk = bs1[col];
        #pragma unroll
        for (int et = 0; et < 4; ++et)
            #pragma unroll
            for (int r = 0; r < 4; ++r)
                sm[OFF_SIN + col*65 + et*16 + (kg << 2) + r] = fmaxf(accv[et][r] + bk, 0.0f);
    }
    __syncthreads();

    // edge_feat = t1 @ Ws2 + bs2 -> ef [o][e] at OFF_E1
    {
        float a2[8];
        #pragma unroll
        for (int u = 0; u < 8; ++u) a2[u] = bs2[og*8 + u];
        for (int k = 0; k < 128; ++k) {
            const float x = sm[OFF_SIN + k*65 + e];
            const float* wr = &Ws2[k*64 + og*8];
            #pragma unroll
            for (int u = 0; u < 8; ++u) a2[u] = fmaf(x, wr[u], a2[u]);
        }
        #pragma unroll
        for (int u = 0; u < 8; ++u) sm[OFF_E1 + (og*8+u)*64 + e] = a2[u];
    }
    __syncthreads();

    // v = silu(ef @ Wc1 + bc1) -> OFF_G2 [f][e]
    {
        float a3[8];
        #pragma unroll
        for (int u = 0; u < 8; ++u) a3[u] = bc1[og*8 + u];
        for (int q = 0; q < 64; ++q) {
            const float x = sm[OFF_E1 + q*64 + e];
            const float* wr = &Wc1[q*64 + og*8];
            #pragma unroll
            for (int u = 0; u < 8; ++u) a3[u] = fmaf(x, wr[u], a3[u]);
        }
        #pragma unroll
        for (int u = 0; u < 8; ++u) sm[OFF_G2 + (og*8+u)*64 + e] = siluf(a3[u]);
    }
    __syncthreads();

    // coord weight + scatter num/cnt
    if (t < 64 && e0 + t < EE) {
        float cw = 0.0f;
        for (int f = 0; f < 64; ++f) cw = fmaf(sm[OFF_G2 + f*64 + t], Wc2[f], cw);
        const int r = s_row[t];
        atomicAdd(&ws[WS_NUM + r*3 + 0], s_cd[t]     * cw);
        atomicAdd(&ws[WS_NUM + r*3 + 1], s_cd[64+t]  * cw);
        atomicAdd(&ws[WS_NUM + r*3 + 2], s_cd[128+t] * cw);
        atomicAdd(&ws[WS_CNT + r], 1.0f);
    }
    // scatter agg (edge_feat per row)
    if (e0 + e < EE) {
        const int r = s_row[e];
        #pragma unroll
        for (int u = 0; u < 8; ++u) {
            const int o = og*8 + u;
            atomicAdd(&ws[WS_AGG + r*64 + o], sm[OFF_E1 + o*64 + e]);
        }
    }
}

__global__ __launch_bounds__(256, 2)
void egcl_node_kernel(const float* __restrict__ h, const float* __restrict__ coord,
                      const int* __restrict__ ei,
                      const float* __restrict__ Wn1, const float* __restrict__ bn1,
                      const float* __restrict__ Wn2, const float* __restrict__ bn2,
                      const float* __restrict__ ws, float* __restrict__ out)
{
    __shared__ float s_m[131*32];
    __shared__ float s_z[64*32];
    const int t = threadIdx.x;
    const int n0 = blockIdx.x * 32;

    {
        const int n = t >> 3, seg = t & 7;
        const float* hp = &h[(n0+n)*64 + seg*8];
        #pragma unroll
        for (int u = 0; u < 8; ++u) s_m[(seg*8+u)*32 + n] = hp[u];
        const float* ap = &ws[WS_AGG + (n0+n)*64 + seg*8];
        #pragma unroll
        for (int u = 0; u < 8; ++u) s_m[(67+seg*8+u)*32 + n] = ap[u];
    }
    if (t < 32) {
        const int n = n0 + t;
        const int r = ei[n], c = ei[EE + n];
        const float dx = coord[r*3+0] - coord[c*3+0];
        const float dy = coord[r*3+1] - coord[c*3+1];
        const float dz = coord[r*3+2] - coord[c*3+2];
        const float inv = 1.0f / (sqrtf(dx*dx + dy*dy + dz*dz) + 1e-8f);
        s_m[64*32 + t] = dx*inv;
        s_m[65*32 + t] = dy*inv;
        s_m[66*32 + t] = dz*inv;
        const float cnt = fmaxf(ws[WS_CNT + n], 1.0f);
        out[NN*67 + n*3 + 0] = coord[n*3+0] + ws[WS_NUM + n*3 + 0] / cnt;
        out[NN*67 + n*3 + 1] = coord[n*3+1] + ws[WS_NUM + n*3 + 1] / cnt;
        out[NN*67 + n*3 + 2] = coord[n*3+2] + ws[WS_NUM + n*3 + 2] / cnt;
    }
    __syncthreads();

    {
        const int n = t & 31, og = t >> 5;
        float acc[8];
        #pragma unroll
        for (int u = 0; u < 8; ++u) acc[u] = bn1[og*8 + u];
        for (int q = 0; q < 131; ++q) {
            const float x = s_m[q*32 + n];
            const float* wr = &Wn1[q*64 + og*8];
            #pragma unroll
            for (int u = 0; u < 8; ++u) acc[u] = fmaf(x, wr[u], acc[u]);
        }
        #pragma unroll
        for (int u = 0; u < 8; ++u) s_z[(og*8+u)*32 + n] = siluf(acc[u]);
    }
    __syncthreads();

    {
        const int n = t & 31, og = t >> 5;
        for (int o = og; o < 67; o += 8) {
            float a = s_m[o*32 + n] + bn2[o];
            for (int k = 0; k < 64; ++k)
                a = fmaf(s_z[k*32 + n], Wn2[k*67 + o], a);
            out[(n0 + n)*67 + o] = a;
        }
    }
}

extern "C" void kernel_launch(void* const* d_in, const int* in_sizes, int n_in,
                              void* d_out, int out_size, void* d_ws, size_t ws_size,
                              hipStream_t stream)
{
    (void)in_sizes; (void)n_in; (void)out_size;
    const float* h     = (const float*)d_in[0];
    const float* coord = (const float*)d_in[1];
    const int*   ei    = (const int*)d_in[2];
    const float* We1   = (const float*)d_in[3];
    const float* be1   = (const float*)d_in[4];
    const float* We2   = (const float*)d_in[5];
    const float* be2   = (const float*)d_in[6];
    const float* Ws1   = (const float*)d_in[7];
    const float* bs1   = (const float*)d_in[8];
    const float* Ws2   = (const float*)d_in[9];
    const float* bs2   = (const float*)d_in[10];
    const float* Wc1   = (const float*)d_in[11];
    const float* bc1   = (const float*)d_in[12];
    const float* Wc2   = (const float*)d_in[13];
    const float* Wn1   = (const float*)d_in[14];
    const float* bn1   = (const float*)d_in[15];
    const float* Wn2   = (const float*)d_in[16];
    const float* bn2   = (const float*)d_in[17];
    float* ws  = (float*)d_ws;
    float* out = (float*)d_out;

    const size_t need = (size_t)WS_TOTAL * sizeof(float) + (size_t)WS1S_ELEMS * 2;
    unsigned short* ws1s = (ws_size >= need) ? (unsigned short*)(ws + WS_TOTAL)
                                             : (unsigned short*)d_out;  // node kernel rewrites d_out afterwards

    hipMemsetAsync(d_ws, 0, (size_t)WS_TOTAL * sizeof(float), stream);
    swz_ws1<<<256, 256, 0, stream>>>(Ws1, ws1s);
    egcl_edge_kernel<<<(EE + 63)/64, 512, 0, stream>>>(h, coord, ei, We1, be1, We2, be2,
                                                       ws1s, bs1, Ws2, bs2, Wc1, bc1, Wc2, ws);
    egcl_node_kernel<<<NN/32, 256, 0, stream>>>(h, coord, ei, Wn1, bn1, Wn2, bn2, ws, out);
}

// Round 6
// 252.022 us; speedup vs baseline: 1.1220x; 1.1118x over previous
//
#include <hip/hip_runtime.h>

#define NN 20000
#define EE 20000

typedef __attribute__((ext_vector_type(8))) short short8;
typedef __attribute__((ext_vector_type(4))) float f32x4;

// workspace layout (float indices)
#define WS_EF     0                         // edge_feat [E][64]
#define WS_TRANS  (WS_EF + EE*64)           // trans [E][3]
#define WS_CNTI   (WS_TRANS + EE*3)         // int cnt[N]   (histogram)
#define WS_OFF    (WS_CNTI + NN)            // int off[N+1] (CSR offsets)
#define WS_CUR    (WS_OFF + NN + 1)         // int cursor[N]
#define WS_EIDX   (WS_CUR + NN)             // int eidx[E]
#define WS_CORE_END (WS_EIDX + EE)
#define WS1S_ELEMS (4096*128)               // bf16 elems of swizzled 64*Ws1 (1 MB)

// LDS float offsets (edge kernel)
#define OFF_SIN  0       // s_in [64][129]=8256 ; B dbuf 2x8KB during GEMM ; t1 [128][65]=8320 after
#define OFF_E1   8320    // e1 [64 f][64 e] ; later ef [64 o][64 e]   (4096)
#define OFF_G2   12416   // g f32 [64 i][64 e] ; later v [64 f][64 e] (4096)
#define OFF_GBF  16512   // g bf16 swizzled [64 e][128 B]             (2048)
#define SM_FLOATS 18560  // 74.2 KB

__device__ __forceinline__ float siluf(float x) {
    return x * (1.0f / (1.0f + __expf(-x)));
}
__device__ __forceinline__ unsigned short f2bf(float f) {
    union { float f; unsigned u; } v; v.f = f;
    return (unsigned short)((v.u + 0x7FFF + ((v.u >> 16) & 1)) >> 16);
}
// async 16B/lane global->LDS; lds base must be wave-uniform (HW adds lane*16)
__device__ __forceinline__ void stage16(const void* gsrc, void* lds_wave_base) {
    __builtin_amdgcn_global_load_lds(
        (const __attribute__((address_space(1))) unsigned int*)gsrc,
        (__attribute__((address_space(3))) unsigned int*)lds_wave_base, 16, 0, 0);
}

// ---------- CSR build ----------
__global__ void hist_csr(const int* __restrict__ ei, int* __restrict__ cnt) {
    const int e = blockIdx.x * 256 + threadIdx.x;
    if (e < EE) atomicAdd(&cnt[ei[e]], 1);
}

__global__ void scan_csr(const int* __restrict__ cnt, int* __restrict__ off,
                         int* __restrict__ cursor) {
    const int t = threadIdx.x;        // 1024 threads, 20 items each
    __shared__ int ps[1024];
    int loc[20];
    int s = 0;
    const int base = t * 20;
    #pragma unroll
    for (int k = 0; k < 20; ++k) {
        const int i = base + k;
        const int c = (i < NN) ? cnt[i] : 0;
        loc[k] = s; s += c;
    }
    ps[t] = s;
    __syncthreads();
    for (int d = 1; d < 1024; d <<= 1) {
        const int v = (t >= d) ? ps[t - d] : 0;
        __syncthreads();
        ps[t] += v;
        __syncthreads();
    }
    const int excl = ps[t] - s;
    #pragma unroll
    for (int k = 0; k < 20; ++k) {
        const int i = base + k;
        if (i < NN) { const int v = excl + loc[k]; off[i] = v; cursor[i] = v; }
    }
    if (t == 1023) off[NN] = ps[1023];
}

__global__ void fill_csr(const int* __restrict__ ei, int* __restrict__ cursor,
                         int* __restrict__ eidx) {
    const int e = blockIdx.x * 256 + threadIdx.x;
    if (e < EE) {
        const int p = atomicAdd(&cursor[ei[e]], 1);
        eidx[p] = e;
    }
}

// out[((s*8+tn)*64 + l)*8 + u] = bf16(64*Ws1[(s*32 + 8*(l>>4) + u)][tn*16 + (l&15)])
__global__ void swz_ws1(const float* __restrict__ Ws1, unsigned short* __restrict__ out) {
    const int tid = blockIdx.x * 256 + threadIdx.x;   // 65536 threads
    const int l = tid & 63, fid = tid >> 6;
    const int s = fid >> 3, tn = fid & 7;
    const int krow = s * 32 + 8 * (l >> 4);
    const int ncol = tn * 16 + (l & 15);
    short8 frag;
    #pragma unroll
    for (int u = 0; u < 8; ++u)
        frag[u] = (short)f2bf(64.0f * Ws1[(krow + u) * 128 + ncol]);
    *(short8*)&out[(size_t)tid * 8] = frag;
}

__global__ __launch_bounds__(512, 2)
void egcl_edge_kernel(const float* __restrict__ h, const float* __restrict__ coord,
                      const int* __restrict__ ei,
                      const float* __restrict__ We1, const float* __restrict__ be1,
                      const float* __restrict__ We2, const float* __restrict__ be2,
                      const unsigned short* __restrict__ Ws1s, const float* __restrict__ bs1,
                      const float* __restrict__ Ws2, const float* __restrict__ bs2,
                      const float* __restrict__ Wc1, const float* __restrict__ bc1,
                      const float* __restrict__ Wc2,
                      float* __restrict__ ef_out, float* __restrict__ trans_out)
{
    __shared__ __attribute__((aligned(16))) float sm[SM_FLOATS];
    __shared__ int s_row[64], s_col[64];
    __shared__ float s_cd[192], s_rad[64];

    const int t = threadIdx.x;
    const int e0 = blockIdx.x * 64;

    if (t < 64) {
        const int eid = min(e0 + t, EE - 1);
        const int r = ei[eid], c = ei[EE + eid];
        s_row[t] = r; s_col[t] = c;
        const float dx = coord[r*3+0] - coord[c*3+0];
        const float dy = coord[r*3+1] - coord[c*3+1];
        const float dz = coord[r*3+2] - coord[c*3+2];
        s_cd[t] = dx; s_cd[64+t] = dy; s_cd[128+t] = dz;
        s_rad[t] = dx*dx + dy*dy + dz*dz;
    }
    __syncthreads();

    // MLP thread mapping: e = t>>3, og = t&7 (og lane-varying -> coalesced weight loads)
    const int e = t >> 3, og = t & 7;

    // gather: s_in[e][129] = [h[row], h[col], radial]
    {
        const int r = s_row[e], c = s_col[e];
        float* din = &sm[OFF_SIN + e*129];
        #pragma unroll
        for (int u = 0; u < 8; ++u) din[og*8 + u] = h[r*64 + og*8 + u];
        #pragma unroll
        for (int u = 0; u < 8; ++u) din[64 + og*8 + u] = h[c*64 + og*8 + u];
        if (og == 0) din[128] = s_rad[e];
    }
    __syncthreads();

    // e1 = silu(in @ We1 + be1) -> OFF_E1 [feat][edge]
    {
        float acc[8];
        #pragma unroll
        for (int u = 0; u < 8; ++u) acc[u] = be1[og*8 + u];
        const float* din = &sm[OFF_SIN + e*129];
        for (int q = 0; q < 129; ++q) {
            const float x = din[q];
            const float* wr = &We1[q*64 + og*8];
            #pragma unroll
            for (int u = 0; u < 8; ++u) acc[u] = fmaf(x, wr[u], acc[u]);
        }
        #pragma unroll
        for (int u = 0; u < 8; ++u) sm[OFF_E1 + (og*8+u)*64 + e] = siluf(acc[u]);
    }
    __syncthreads();

    // g = silu(e1 @ We2 + be2) -> f32 [i][e] at OFF_G2, bf16 swizzled [e][k] at OFF_GBF
    {
        float acc[8];
        #pragma unroll
        for (int u = 0; u < 8; ++u) acc[u] = be2[og*8 + u];
        for (int q = 0; q < 64; ++q) {
            const float x = sm[OFF_E1 + q*64 + e];
            const float* wr = &We2[q*64 + og*8];
            #pragma unroll
            for (int u = 0; u < 8; ++u) acc[u] = fmaf(x, wr[u], acc[u]);
        }
        short8 frag;
        #pragma unroll
        for (int u = 0; u < 8; ++u) {
            const float s = siluf(acc[u]);
            sm[OFF_G2 + (og*8+u)*64 + e] = s;
            frag[u] = (short)f2bf(s);
        }
        *(short8*)((char*)sm + OFF_GBF*4 + e*128 + ((og ^ (e & 7)) * 16)) = frag;
    }
    __syncthreads();

    // ---- SO3 GEMM: acc[e,k] = sum_i g[e,i] * (g_bf16[e,:] @ 64*Ws1_i[:,k])
    // Wave w owns cols [w*16,+16). 128 steps x 8KB of B, double-buffered LDS,
    // barrier-synchronized (safe: __syncthreads drains vmcnt before s_barrier).
    const int l = t & 63, w = t >> 6;
    const int kg = l >> 4;

    short8 A[4][2];
    #pragma unroll
    for (int et = 0; et < 4; ++et) {
        const int er = et*16 + (l & 15);
        #pragma unroll
        for (int kh = 0; kh < 2; ++kh)
            A[et][kh] = *(const short8*)((const char*)sm + OFF_GBF*4 + er*128 +
                                         (((kh*4 + kg) ^ (er & 7)) * 16));
    }

    float accv[4][4];
    #pragma unroll
    for (int et = 0; et < 4; ++et)
        #pragma unroll
        for (int r = 0; r < 4; ++r) accv[et][r] = 0.0f;

    const char* Bsrc = (const char*)Ws1s;
    char* const buf0 = (char*)sm;           // 8KB
    char* const buf1 = (char*)sm + 8192;    // 8KB
    char* const wsl0 = buf0 + w*1024;       // wave-uniform dst slice
    char* const wsl1 = buf1 + w*1024;
    const int lane16 = l * 16;

    // prologue: stage step 0 -> buf0 (each thread its own 16B)
    stage16(Bsrc + t*16, wsl0);
    __syncthreads();

    f32x4 ci[4];
    #pragma unroll 1
    for (int m = 0; m < 64; ++m) {
        // stage odd step 2m+1 -> buf1 (hides under the even-step MFMAs)
        stage16(Bsrc + (size_t)(2*m+1)*8192 + t*16, wsl1);
        {   // even step 2m from buf0 (K rows [0,32) of i-block m)
            const short8 b0 = *(const short8*)(wsl0 + lane16);
            #pragma unroll
            for (int et = 0; et < 4; ++et)
                ci[et] = __builtin_amdgcn_mfma_f32_16x16x32_bf16(A[et][0], b0, (f32x4){0.f,0.f,0.f,0.f}, 0, 0, 0);
        }
        __syncthreads();   // buf1 staged & landed; all waves done reading buf0
        if (m < 63) stage16(Bsrc + (size_t)(2*m+2)*8192 + t*16, wsl0);
        {   // odd step 2m+1 from buf1 (K rows [32,64))
            const short8 b1 = *(const short8*)(wsl1 + lane16);
            #pragma unroll
            for (int et = 0; et < 4; ++et)
                ci[et] = __builtin_amdgcn_mfma_f32_16x16x32_bf16(A[et][1], b1, ci[et], 0, 0, 0);
        }
        {   // merge i-block m: accv += g[e,m] * ci
            #pragma unroll
            for (int et = 0; et < 4; ++et) {
                const f32x4 g4 = *(const f32x4*)&sm[OFF_G2 + m*64 + et*16 + (kg << 2)];
                #pragma unroll
                for (int r = 0; r < 4; ++r) accv[et][r] = fmaf(g4[r], ci[et][r], accv[et][r]);
            }
        }
        __syncthreads();   // buf0 staged & landed; all waves done reading buf1
    }

    // t1 = relu(acc + bs1) -> OFF_SIN region, [col][65]
    {
        const int col = w*16 + (l & 15);
        const float bk = bs1[col];
        #pragma unroll
        for (int et = 0; et < 4; ++et)
            #pragma unroll
            for (int r = 0; r < 4; ++r)
                sm[OFF_SIN + col*65 + et*16 + (kg << 2) + r] = fmaxf(accv[et][r] + bk, 0.0f);
    }
    __syncthreads();

    // edge_feat = t1 @ Ws2 + bs2 -> ef [o][e] at OFF_E1
    {
        float a2[8];
        #pragma unroll
        for (int u = 0; u < 8; ++u) a2[u] = bs2[og*8 + u];
        for (int k = 0; k < 128; ++k) {
            const float x = sm[OFF_SIN + k*65 + e];
            const float* wr = &Ws2[k*64 + og*8];
            #pragma unroll
            for (int u = 0; u < 8; ++u) a2[u] = fmaf(x, wr[u], a2[u]);
        }
        #pragma unroll
        for (int u = 0; u < 8; ++u) sm[OFF_E1 + (og*8+u)*64 + e] = a2[u];
    }
    __syncthreads();

    // v = silu(ef @ Wc1 + bc1) -> OFF_G2 [f][e]
    {
        float a3[8];
        #pragma unroll
        for (int u = 0; u < 8; ++u) a3[u] = bc1[og*8 + u];
        for (int q = 0; q < 64; ++q) {
            const float x = sm[OFF_E1 + q*64 + e];
            const float* wr = &Wc1[q*64 + og*8];
            #pragma unroll
            for (int u = 0; u < 8; ++u) a3[u] = fmaf(x, wr[u], a3[u]);
        }
        #pragma unroll
        for (int u = 0; u < 8; ++u) sm[OFF_G2 + (og*8+u)*64 + e] = siluf(a3[u]);
    }
    __syncthreads();

    // coord weight -> dense trans write (NO atomics)
    if (t < 64 && e0 + t < EE) {
        float cw = 0.0f;
        for (int f = 0; f < 64; ++f) cw = fmaf(sm[OFF_G2 + f*64 + t], Wc2[f], cw);
        const int eid = e0 + t;
        trans_out[eid*3 + 0] = s_cd[t]     * cw;
        trans_out[eid*3 + 1] = s_cd[64+t]  * cw;
        trans_out[eid*3 + 2] = s_cd[128+t] * cw;
    }
    // dense edge_feat write (coalesced, NO atomics)
    if (e0 + e < EE) {
        float* dst = &ef_out[(size_t)(e0 + e)*64 + og*8];
        #pragma unroll
        for (int u = 0; u < 8; ++u) dst[u] = sm[OFF_E1 + (og*8+u)*64 + e];
    }
}

__global__ __launch_bounds__(256, 2)
void egcl_node_kernel(const float* __restrict__ h, const float* __restrict__ coord,
                      const int* __restrict__ ei,
                      const float* __restrict__ Wn1, const float* __restrict__ bn1,
                      const float* __restrict__ Wn2, const float* __restrict__ bn2,
                      const float* __restrict__ ef, const float* __restrict__ trans,
                      const int* __restrict__ off, const int* __restrict__ eidx,
                      float* __restrict__ out)
{
    __shared__ float s_m[131*32];
    __shared__ float s_z[64*32];
    const int t = threadIdx.x;
    const int n0 = blockIdx.x * 32;
    const int n = t >> 3, og = t & 7;
    const int gn = n0 + n;

    // h -> s_m rows 0..63
    {
        const float* hp = &h[gn*64 + og*8];
        #pragma unroll
        for (int u = 0; u < 8; ++u) s_m[(og*8+u)*32 + n] = hp[u];
    }
    // CSR gather: agg (rows 67..130) + num/cnt -> coord_out
    {
        const int o0 = off[gn], o1 = off[gn + 1];
        float acc[8];
        #pragma unroll
        for (int u = 0; u < 8; ++u) acc[u] = 0.0f;
        float nx = 0.0f, ny = 0.0f, nz = 0.0f;
        for (int j = o0; j < o1; ++j) {
            const int e2 = eidx[j];
            const float* ep = &ef[(size_t)e2*64 + og*8];
            #pragma unroll
            for (int u = 0; u < 8; ++u) acc[u] += ep[u];
            if (og == 0) {
                nx += trans[e2*3 + 0];
                ny += trans[e2*3 + 1];
                nz += trans[e2*3 + 2];
            }
        }
        #pragma unroll
        for (int u = 0; u < 8; ++u) s_m[(67+og*8+u)*32 + n] = acc[u];
        if (og == 0) {
            const float cnt = fmaxf((float)(o1 - o0), 1.0f);
            out[NN*67 + gn*3 + 0] = coord[gn*3 + 0] + nx / cnt;
            out[NN*67 + gn*3 + 1] = coord[gn*3 + 1] + ny / cnt;
            out[NN*67 + gn*3 + 2] = coord[gn*3 + 2] + nz / cnt;
        }
    }
    // rel for node n comes from edge n (E == N quirk)
    if (t < 32) {
        const int nn2 = n0 + t;
        const int r = ei[nn2], c = ei[EE + nn2];
        const float dx = coord[r*3+0] - coord[c*3+0];
        const float dy = coord[r*3+1] - coord[c*3+1];
        const float dz = coord[r*3+2] - coord[c*3+2];
        const float inv = 1.0f / (sqrtf(dx*dx + dy*dy + dz*dz) + 1e-8f);
        s_m[64*32 + t] = dx*inv;
        s_m[65*32 + t] = dy*inv;
        s_m[66*32 + t] = dz*inv;
    }
    __syncthreads();

    // z = silu(m @ Wn1 + bn1)
    {
        float acc[8];
        #pragma unroll
        for (int u = 0; u < 8; ++u) acc[u] = bn1[og*8 + u];
        for (int q = 0; q < 131; ++q) {
            const float x = s_m[q*32 + n];
            const float* wr = &Wn1[q*64 + og*8];
            #pragma unroll
            for (int u = 0; u < 8; ++u) acc[u] = fmaf(x, wr[u], acc[u]);
        }
        #pragma unroll
        for (int u = 0; u < 8; ++u) s_z[(og*8+u)*32 + n] = siluf(acc[u]);
    }
    __syncthreads();

    // h_out = h_pos + z @ Wn2 + bn2   (h_pos == m[0:67])
    {
        for (int o = og; o < 67; o += 8) {
            float a = s_m[o*32 + n] + bn2[o];
            for (int k = 0; k < 64; ++k)
                a = fmaf(s_z[k*32 + n], Wn2[k*67 + o], a);
            out[gn*67 + o] = a;
        }
    }
}

extern "C" void kernel_launch(void* const* d_in, const int* in_sizes, int n_in,
                              void* d_out, int out_size, void* d_ws, size_t ws_size,
                              hipStream_t stream)
{
    (void)in_sizes; (void)n_in; (void)out_size;
    const float* h     = (const float*)d_in[0];
    const float* coord = (const float*)d_in[1];
    const int*   ei    = (const int*)d_in[2];
    const float* We1   = (const float*)d_in[3];
    const float* be1   = (const float*)d_in[4];
    const float* We2   = (const float*)d_in[5];
    const float* be2   = (const float*)d_in[6];
    const float* Ws1   = (const float*)d_in[7];
    const float* bs1   = (const float*)d_in[8];
    const float* Ws2   = (const float*)d_in[9];
    const float* bs2   = (const float*)d_in[10];
    const float* Wc1   = (const float*)d_in[11];
    const float* bc1   = (const float*)d_in[12];
    const float* Wc2   = (const float*)d_in[13];
    const float* Wn1   = (const float*)d_in[14];
    const float* bn1   = (const float*)d_in[15];
    const float* Wn2   = (const float*)d_in[16];
    const float* bn2   = (const float*)d_in[17];
    float* ws  = (float*)d_ws;
    float* out = (float*)d_out;

    float* ef    = ws + WS_EF;
    float* trans = ws + WS_TRANS;
    int* cnti = (int*)(ws + WS_CNTI);
    int* off  = (int*)(ws + WS_OFF);
    int* cur  = (int*)(ws + WS_CUR);
    int* eidx = (int*)(ws + WS_EIDX);

    const size_t need_all = (size_t)WS_CORE_END * sizeof(float) + (size_t)WS1S_ELEMS * 2;
    unsigned short* ws1s = (ws_size >= need_all) ? (unsigned short*)(ws + WS_CORE_END)
                                                 : (unsigned short*)d_out;  // node kernel rewrites d_out afterwards

    hipMemsetAsync((void*)cnti, 0, (size_t)NN * sizeof(int), stream);
    hist_csr<<<(EE + 255)/256, 256, 0, stream>>>(ei, cnti);
    scan_csr<<<1, 1024, 0, stream>>>(cnti, off, cur);
    fill_csr<<<(EE + 255)/256, 256, 0, stream>>>(ei, cur, eidx);
    swz_ws1<<<256, 256, 0, stream>>>(Ws1, ws1s);
    egcl_edge_kernel<<<(EE + 63)/64, 512, 0, stream>>>(h, coord, ei, We1, be1, We2, be2,
                                                       ws1s, bs1, Ws2, bs2, Wc1, bc1, Wc2,
                                                       ef, trans);
    egcl_node_kernel<<<NN/32, 256, 0, stream>>>(h, coord, ei, Wn1, bn1, Wn2, bn2,
                                                ef, trans, off, eidx, out);
}